// Round 1
// baseline (3649.913 us; speedup 1.0000x reference)
//
#include <hip/hip_runtime.h>

// EquivariantGraphConvCheap: N=50000 nodes, E=500000 edges, H=128.
// out[n,0,:] = x[n,0,:]@Ws_root^T + b + (sum_{e: row=n} x[col,0,:])@Ws_rel^T
// out[n,v,:] = x[n,v,:]@Wv_root^T +     (sum_{e: row=n} x[col,v,:])@Wv_rel^T
// Linearity: aggregate RAW features first (scatter-add), transform per node.

// ---------------- Phase 1: edge scatter-add (raw features) ----------------
// thread = (edge, k) where k indexes 128 float4 chunks of the 512-float row.
__global__ __launch_bounds__(256) void scatter_add_kernel(
    const float4* __restrict__ x4,
    const int* __restrict__ ei,   // [2][E] int32
    float* __restrict__ out,
    int E)
{
    long long w = (long long)blockIdx.x * 256 + threadIdx.x;
    int e = (int)(w >> 7);
    int k = (int)(w & 127);
    if (e >= E) return;
    int row = ei[e];
    int col = ei[E + e];
    float4 v = x4[(long long)col * 128 + k];
    float* dst = out + (long long)row * 512 + (k << 2);
    atomicAdd(dst + 0, v.x);
    atomicAdd(dst + 1, v.y);
    atomicAdd(dst + 2, v.z);
    atomicAdd(dst + 3, v.w);
}

// ---------------- Phase 2: node transform (tiled fp32 GEMM) ----------------
// Rows: CHAN=0 -> scalar rows r=n (offset n*512); CHAN=1 -> vector rows
// r=n*3+v (offset n*512+128+v*128). out holds agg on entry; final on exit.
// C[r,o] = sum_h Aroot[r,h]*Wroot[o,h] + sum_h Agg[r,h]*Wrel[o,h] (+bias)
// Tile: 128 rows x 128 cols, BK=32, 256 threads, 8x8 micro-tile.

__device__ __forceinline__ int swz(int c) { return c + ((c >> 5) << 2); }  // break 32-aliasing

template<int CHAN>
__global__ __launch_bounds__(256) void transform_kernel(
    const float* __restrict__ x,
    float* __restrict__ out,
    const float* __restrict__ Wroot,
    const float* __restrict__ Wrel,
    const float* __restrict__ bias,
    int M)
{
    __shared__ float As[32][140];  // [kk][m-swizzled]
    __shared__ float Bs[32][140];  // [kk][o-swizzled]
    const int tid = threadIdx.x;
    const int row0 = blockIdx.x * 128;
    const int trow = (tid >> 4) << 3;   // 0..120 step 8
    const int tcol = (tid & 15) << 3;   // 0..120 step 8
    const int trs = swz(trow);
    const int tcs = swz(tcol);

    float acc[8][8];
    #pragma unroll
    for (int i = 0; i < 8; i++)
        #pragma unroll
        for (int j = 0; j < 8; j++) acc[i][j] = 0.f;

    for (int phase = 0; phase < 2; phase++) {
        const float* Aglob = (phase == 0) ? x : out;      // agg lives in out
        const float* W     = (phase == 0) ? Wroot : Wrel;
        for (int kc = 0; kc < 4; kc++) {
            // ---- stage A: 128 rows x 32 k ----
            #pragma unroll
            for (int j = 0; j < 4; j++) {
                int flat4 = tid + j * 256;       // 0..1023
                int r   = flat4 >> 3;            // 0..127
                int kk4 = flat4 & 7;             // 0..7
                int gr = row0 + r;
                float4 v = make_float4(0.f, 0.f, 0.f, 0.f);
                if (gr < M) {
                    size_t base;
                    if (CHAN == 0) base = (size_t)gr * 512;
                    else { int n = gr / 3; int vv = gr - n * 3;
                           base = (size_t)n * 512 + 128 + (size_t)vv * 128; }
                    v = *(const float4*)(Aglob + base + kc * 32 + kk4 * 4);
                }
                int rs = swz(r);
                As[kk4 * 4 + 0][rs] = v.x;
                As[kk4 * 4 + 1][rs] = v.y;
                As[kk4 * 4 + 2][rs] = v.z;
                As[kk4 * 4 + 3][rs] = v.w;
            }
            // ---- stage B: 32 k x 128 o (coalesced along h of W[o][h]) ----
            #pragma unroll
            for (int j = 0; j < 4; j++) {
                int flat4 = tid + j * 256;
                int o   = flat4 >> 3;
                int kk4 = flat4 & 7;
                float4 v = *(const float4*)(W + (size_t)o * 128 + kc * 32 + kk4 * 4);
                int os = swz(o);
                Bs[kk4 * 4 + 0][os] = v.x;
                Bs[kk4 * 4 + 1][os] = v.y;
                Bs[kk4 * 4 + 2][os] = v.z;
                Bs[kk4 * 4 + 3][os] = v.w;
            }
            __syncthreads();
            // ---- compute ----
            #pragma unroll
            for (int kk = 0; kk < 32; kk++) {
                float a[8], b[8];
                #pragma unroll
                for (int i = 0; i < 8; i++) a[i] = As[kk][trs + i];
                #pragma unroll
                for (int j2 = 0; j2 < 8; j2++) b[j2] = Bs[kk][tcs + j2];
                #pragma unroll
                for (int i = 0; i < 8; i++)
                    #pragma unroll
                    for (int j2 = 0; j2 < 8; j2++)
                        acc[i][j2] = fmaf(a[i], b[j2], acc[i][j2]);
            }
            __syncthreads();
        }
    }

    // ---- epilogue ----
    float bb[8];
    #pragma unroll
    for (int j = 0; j < 8; j++) bb[j] = (CHAN == 0) ? bias[tcol + j] : 0.f;

    #pragma unroll
    for (int i = 0; i < 8; i++) {
        int gr = row0 + trow + i;
        if (gr >= M) continue;
        size_t base;
        if (CHAN == 0) base = (size_t)gr * 512;
        else { int n = gr / 3; int vv = gr - n * 3;
               base = (size_t)n * 512 + 128 + (size_t)vv * 128; }
        float4 v0, v1;
        v0.x = acc[i][0] + bb[0]; v0.y = acc[i][1] + bb[1];
        v0.z = acc[i][2] + bb[2]; v0.w = acc[i][3] + bb[3];
        v1.x = acc[i][4] + bb[4]; v1.y = acc[i][5] + bb[5];
        v1.z = acc[i][6] + bb[6]; v1.w = acc[i][7] + bb[7];
        *(float4*)(out + base + tcol)     = v0;
        *(float4*)(out + base + tcol + 4) = v1;
    }
}

extern "C" void kernel_launch(void* const* d_in, const int* in_sizes, int n_in,
                              void* d_out, int out_size, void* d_ws, size_t ws_size,
                              hipStream_t stream) {
    const float* x        = (const float*)d_in[0];
    const int*   ei       = (const int*)d_in[1];
    const float* W_s_rel  = (const float*)d_in[2];
    const float* W_s_root = (const float*)d_in[3];
    const float* b_s_root = (const float*)d_in[4];
    const float* W_v_rel  = (const float*)d_in[5];
    const float* W_v_root = (const float*)d_in[6];
    float* out = (float*)d_out;

    int N = in_sizes[0] / 512;   // 50000
    int E = in_sizes[1] / 2;     // 500000

    hipMemsetAsync(d_out, 0, (size_t)out_size * sizeof(float), stream);

    long long total = (long long)E * 128;
    int blocks = (int)((total + 255) / 256);
    scatter_add_kernel<<<blocks, 256, 0, stream>>>((const float4*)x, ei, out, E);

    int Ms = N;
    transform_kernel<0><<<(Ms + 127) / 128, 256, 0, stream>>>(
        x, out, W_s_root, W_s_rel, b_s_root, Ms);
    int Mv = 3 * N;
    transform_kernel<1><<<(Mv + 127) / 128, 256, 0, stream>>>(
        x, out, W_v_root, W_v_rel, nullptr, Mv);
}

// Round 2
// 587.793 us; speedup vs baseline: 6.2095x; 6.2095x over previous
//
#include <hip/hip_runtime.h>

// EquivariantGraphConvCheap: N=50000, E=500000, H=128.
// Linearity: segment_sum(msg[col] @ W^T, row) == segment_sum(x[col], row) @ W^T.
// R2: replace 256M-atomic scatter (3.3 ms, atomic-throughput bound) with
// device-built CSR + per-node gather-aggregate (no hot-path atomics).

// ---------- CSR build ----------
__global__ __launch_bounds__(256) void hist_kernel(
    const int* __restrict__ ei, int* __restrict__ counts, int E)
{
    int e = blockIdx.x * 256 + threadIdx.x;
    if (e < E) atomicAdd(&counts[ei[e]], 1);
}

// single-block exclusive scan (wave shuffle + LDS combine), writes offsets[0..N]
// and a working copy `cursor` for the binning pass.
__global__ __launch_bounds__(1024) void scan_kernel(
    const int* __restrict__ counts, int* __restrict__ offsets,
    int* __restrict__ cursor, int N)
{
    __shared__ int wsum[16];
    __shared__ int carry_s;
    const int tid = threadIdx.x;
    const int lane = tid & 63, wid = tid >> 6;
    if (tid == 0) carry_s = 0;
    __syncthreads();
    for (int base = 0; base < N; base += 1024) {
        int i = base + tid;
        int v = (i < N) ? counts[i] : 0;
        int incl = v;
        #pragma unroll
        for (int off = 1; off < 64; off <<= 1) {
            int t = __shfl_up(incl, off, 64);
            if (lane >= off) incl += t;
        }
        if (lane == 63) wsum[wid] = incl;
        __syncthreads();
        if (wid == 0) {
            int ws = (lane < 16) ? wsum[lane] : 0;
            int wincl = ws;
            #pragma unroll
            for (int off = 1; off < 16; off <<= 1) {
                int t = __shfl_up(wincl, off, 64);
                if (lane >= off) wincl += t;
            }
            if (lane < 16) wsum[lane] = wincl - ws;  // exclusive wave offset
        }
        __syncthreads();
        int excl = incl - v + wsum[wid] + carry_s;
        if (i < N) { offsets[i] = excl; cursor[i] = excl; }
        __syncthreads();                      // all reads of carry_s/wsum done
        if (tid == 1023) carry_s = excl + v;  // running total through this chunk
        __syncthreads();
    }
    if (threadIdx.x == 0) offsets[N] = carry_s;
}

__global__ __launch_bounds__(256) void bin_kernel(
    const int* __restrict__ ei, int* __restrict__ cursor,
    int* __restrict__ bins, int E)
{
    int e = blockIdx.x * 256 + threadIdx.x;
    if (e < E) {
        int row = ei[e], col = ei[E + e];
        int pos = atomicAdd(&cursor[row], 1);
        bins[pos] = col;
    }
}

// ---------- Phase 1: per-node aggregation (no atomics) ----------
// block = node, thread k in [0,128) owns float4 chunk k of the 512-f row.
__global__ __launch_bounds__(128) void aggregate_kernel(
    const float4* __restrict__ x4, const int* __restrict__ offsets,
    const int* __restrict__ bins, float4* __restrict__ out4)
{
    const int n = blockIdx.x;
    const int k = threadIdx.x;
    const int beg = offsets[n], end = offsets[n + 1];
    float4 acc = make_float4(0.f, 0.f, 0.f, 0.f);
    int e = beg;
    for (; e + 2 <= end; e += 2) {
        int c0 = bins[e], c1 = bins[e + 1];
        float4 v0 = x4[(size_t)c0 * 128 + k];
        float4 v1 = x4[(size_t)c1 * 128 + k];
        acc.x += v0.x; acc.y += v0.y; acc.z += v0.z; acc.w += v0.w;
        acc.x += v1.x; acc.y += v1.y; acc.z += v1.z; acc.w += v1.w;
    }
    if (e < end) {
        int c = bins[e];
        float4 v = x4[(size_t)c * 128 + k];
        acc.x += v.x; acc.y += v.y; acc.z += v.z; acc.w += v.w;
    }
    out4[(size_t)n * 128 + k] = acc;
}

// ---------- Phase 2: node transform (tiled fp32 GEMM, in-place on out) ----------
__device__ __forceinline__ int swz(int c) { return c + ((c >> 5) << 2); }

template<int CHAN>
__global__ __launch_bounds__(256) void transform_kernel(
    const float* __restrict__ x,
    float* __restrict__ out,
    const float* __restrict__ Wroot,
    const float* __restrict__ Wrel,
    const float* __restrict__ bias,
    int M)
{
    __shared__ float As[32][140];
    __shared__ float Bs[32][140];
    const int tid = threadIdx.x;
    const int row0 = blockIdx.x * 128;
    const int trow = (tid >> 4) << 3;
    const int tcol = (tid & 15) << 3;
    const int trs = swz(trow);
    const int tcs = swz(tcol);

    float acc[8][8];
    #pragma unroll
    for (int i = 0; i < 8; i++)
        #pragma unroll
        for (int j = 0; j < 8; j++) acc[i][j] = 0.f;

    for (int phase = 0; phase < 2; phase++) {
        const float* Aglob = (phase == 0) ? x : out;
        const float* W     = (phase == 0) ? Wroot : Wrel;
        for (int kc = 0; kc < 4; kc++) {
            #pragma unroll
            for (int j = 0; j < 4; j++) {
                int flat4 = tid + j * 256;
                int r = flat4 >> 3;
                int kk4 = flat4 & 7;
                int gr = row0 + r;
                float4 v = make_float4(0.f, 0.f, 0.f, 0.f);
                if (gr < M) {
                    size_t base;
                    if (CHAN == 0) base = (size_t)gr * 512;
                    else { int n = gr / 3; int vv = gr - n * 3;
                           base = (size_t)n * 512 + 128 + (size_t)vv * 128; }
                    v = *(const float4*)(Aglob + base + kc * 32 + kk4 * 4);
                }
                int rs = swz(r);
                As[kk4 * 4 + 0][rs] = v.x;
                As[kk4 * 4 + 1][rs] = v.y;
                As[kk4 * 4 + 2][rs] = v.z;
                As[kk4 * 4 + 3][rs] = v.w;
            }
            #pragma unroll
            for (int j = 0; j < 4; j++) {
                int flat4 = tid + j * 256;
                int o = flat4 >> 3;
                int kk4 = flat4 & 7;
                float4 v = *(const float4*)(W + (size_t)o * 128 + kc * 32 + kk4 * 4);
                int os = swz(o);
                Bs[kk4 * 4 + 0][os] = v.x;
                Bs[kk4 * 4 + 1][os] = v.y;
                Bs[kk4 * 4 + 2][os] = v.z;
                Bs[kk4 * 4 + 3][os] = v.w;
            }
            __syncthreads();
            #pragma unroll
            for (int kk = 0; kk < 32; kk++) {
                float a[8], b[8];
                #pragma unroll
                for (int i = 0; i < 8; i++) a[i] = As[kk][trs + i];
                #pragma unroll
                for (int j2 = 0; j2 < 8; j2++) b[j2] = Bs[kk][tcs + j2];
                #pragma unroll
                for (int i = 0; i < 8; i++)
                    #pragma unroll
                    for (int j2 = 0; j2 < 8; j2++)
                        acc[i][j2] = fmaf(a[i], b[j2], acc[i][j2]);
            }
            __syncthreads();
        }
    }

    float bb[8];
    #pragma unroll
    for (int j = 0; j < 8; j++) bb[j] = (CHAN == 0) ? bias[tcol + j] : 0.f;

    #pragma unroll
    for (int i = 0; i < 8; i++) {
        int gr = row0 + trow + i;
        if (gr >= M) continue;
        size_t base;
        if (CHAN == 0) base = (size_t)gr * 512;
        else { int n = gr / 3; int vv = gr - n * 3;
               base = (size_t)n * 512 + 128 + (size_t)vv * 128; }
        float4 v0, v1;
        v0.x = acc[i][0] + bb[0]; v0.y = acc[i][1] + bb[1];
        v0.z = acc[i][2] + bb[2]; v0.w = acc[i][3] + bb[3];
        v1.x = acc[i][4] + bb[4]; v1.y = acc[i][5] + bb[5];
        v1.z = acc[i][6] + bb[6]; v1.w = acc[i][7] + bb[7];
        *(float4*)(out + base + tcol)     = v0;
        *(float4*)(out + base + tcol + 4) = v1;
    }
}

extern "C" void kernel_launch(void* const* d_in, const int* in_sizes, int n_in,
                              void* d_out, int out_size, void* d_ws, size_t ws_size,
                              hipStream_t stream) {
    const float* x        = (const float*)d_in[0];
    const int*   ei       = (const int*)d_in[1];
    const float* W_s_rel  = (const float*)d_in[2];
    const float* W_s_root = (const float*)d_in[3];
    const float* b_s_root = (const float*)d_in[4];
    const float* W_v_rel  = (const float*)d_in[5];
    const float* W_v_root = (const float*)d_in[6];
    float* out = (float*)d_out;

    int N = in_sizes[0] / 512;   // 50000
    int E = in_sizes[1] / 2;     // 500000

    // workspace layout (ints): counts[N] | offsets[N+1] | cursor[N] | bins[E]
    int* counts  = (int*)d_ws;
    int* offsets = counts + N;
    int* cursor  = offsets + N + 1;
    int* bins    = cursor + N;

    hipMemsetAsync(counts, 0, (size_t)N * sizeof(int), stream);
    hist_kernel<<<(E + 255) / 256, 256, 0, stream>>>(ei, counts, E);
    scan_kernel<<<1, 1024, 0, stream>>>(counts, offsets, cursor, N);
    bin_kernel<<<(E + 255) / 256, 256, 0, stream>>>(ei, cursor, bins, E);

    aggregate_kernel<<<N, 128, 0, stream>>>((const float4*)x, offsets, bins,
                                            (float4*)out);

    transform_kernel<0><<<(N + 127) / 128, 256, 0, stream>>>(
        x, out, W_s_root, W_s_rel, b_s_root, N);
    transform_kernel<1><<<(3 * N + 127) / 128, 256, 0, stream>>>(
        x, out, W_v_root, W_v_rel, nullptr, 3 * N);
}

// Round 3
// 542.344 us; speedup vs baseline: 6.7299x; 1.0838x over previous
//
#include <hip/hip_runtime.h>

// EquivariantGraphConvCheap: N=50000, E=500000, H=128.
// R3: multi-block scan (was single-block ~serial), aggregate unroll-4 (MLP),
// merged transform launch (tail occupancy).

// ---------- CSR build ----------
__global__ __launch_bounds__(256) void hist_kernel(
    const int* __restrict__ ei, int* __restrict__ counts, int E)
{
    int e = blockIdx.x * 256 + threadIdx.x;
    if (e < E) atomicAdd(&counts[ei[e]], 1);
}

// phase 1: per-1024-chunk local exclusive scan + chunk totals
__global__ __launch_bounds__(1024) void scan_local_kernel(
    const int* __restrict__ counts, int* __restrict__ offsets,
    int* __restrict__ blocksums, int N)
{
    __shared__ int wsum[16];
    const int tid = threadIdx.x, lane = tid & 63, wid = tid >> 6;
    int i = blockIdx.x * 1024 + tid;
    int v = (i < N) ? counts[i] : 0;
    int incl = v;
    #pragma unroll
    for (int off = 1; off < 64; off <<= 1) {
        int t = __shfl_up(incl, off, 64);
        if (lane >= off) incl += t;
    }
    if (lane == 63) wsum[wid] = incl;
    __syncthreads();
    if (wid == 0) {
        int ws = (lane < 16) ? wsum[lane] : 0;
        int wincl = ws;
        #pragma unroll
        for (int off = 1; off < 16; off <<= 1) {
            int t = __shfl_up(wincl, off, 64);
            if (lane >= off) wincl += t;
        }
        if (lane < 16) wsum[lane] = wincl - ws;
    }
    __syncthreads();
    int excl = incl - v + wsum[wid];
    if (i < N) offsets[i] = excl;
    if (tid == 1023) blocksums[blockIdx.x] = excl + v;
}

// phase 2: scan the (<=64) chunk totals in one wave
__global__ __launch_bounds__(64) void scan_blocksums_kernel(
    int* __restrict__ bs, int nb)
{
    int lane = threadIdx.x;
    int v = (lane < nb) ? bs[lane] : 0;
    int incl = v;
    #pragma unroll
    for (int off = 1; off < 64; off <<= 1) {
        int t = __shfl_up(incl, off, 64);
        if (lane >= off) incl += t;
    }
    if (lane < nb) bs[lane] = incl - v;
}

// phase 3: add chunk offset, emit offsets + cursor copy
__global__ __launch_bounds__(1024) void scan_add_kernel(
    int* __restrict__ offsets, int* __restrict__ cursor,
    const int* __restrict__ bs, int N, int E)
{
    int i = blockIdx.x * 1024 + threadIdx.x;
    if (i < N) {
        int v = offsets[i] + bs[blockIdx.x];
        offsets[i] = v;
        cursor[i] = v;
    }
    if (i == 0) offsets[N] = E;
}

__global__ __launch_bounds__(256) void bin_kernel(
    const int* __restrict__ ei, int* __restrict__ cursor,
    int* __restrict__ bins, int E)
{
    int e = blockIdx.x * 256 + threadIdx.x;
    if (e < E) {
        int row = ei[e], col = ei[E + e];
        int pos = atomicAdd(&cursor[row], 1);
        bins[pos] = col;
    }
}

// ---------- Phase 1: per-node aggregation (no atomics, 4-deep MLP) ----------
__global__ __launch_bounds__(128) void aggregate_kernel(
    const float4* __restrict__ x4, const int* __restrict__ offsets,
    const int* __restrict__ bins, float4* __restrict__ out4)
{
    const int n = blockIdx.x;
    const int k = threadIdx.x;
    const int beg = offsets[n], end = offsets[n + 1];
    float4 acc = make_float4(0.f, 0.f, 0.f, 0.f);
    int e = beg;
    for (; e + 4 <= end; e += 4) {
        int c0 = bins[e], c1 = bins[e + 1], c2 = bins[e + 2], c3 = bins[e + 3];
        float4 v0 = x4[(size_t)c0 * 128 + k];
        float4 v1 = x4[(size_t)c1 * 128 + k];
        float4 v2 = x4[(size_t)c2 * 128 + k];
        float4 v3 = x4[(size_t)c3 * 128 + k];
        acc.x += v0.x + v1.x + v2.x + v3.x;
        acc.y += v0.y + v1.y + v2.y + v3.y;
        acc.z += v0.z + v1.z + v2.z + v3.z;
        acc.w += v0.w + v1.w + v2.w + v3.w;
    }
    for (; e < end; e++) {
        int c = bins[e];
        float4 v = x4[(size_t)c * 128 + k];
        acc.x += v.x; acc.y += v.y; acc.z += v.z; acc.w += v.w;
    }
    out4[(size_t)n * 128 + k] = acc;
}

// ---------- Phase 2: merged node transform (tiled fp32 GEMM, in-place) ----------
// blocks [0,Bs): scalar rows (M=Ns, row=n, offset n*512)
// blocks [Bs,..): vector rows (M=3*Ns, row=n*3+v, offset n*512+128+v*128)
__device__ __forceinline__ int swz(int c) { return c + ((c >> 5) << 2); }

__global__ __launch_bounds__(256) void transform_kernel(
    const float* __restrict__ x,
    float* __restrict__ out,
    const float* __restrict__ Ws_root, const float* __restrict__ Ws_rel,
    const float* __restrict__ b_s,
    const float* __restrict__ Wv_root, const float* __restrict__ Wv_rel,
    int Ns, int Bs)
{
    __shared__ float As[32][140];
    __shared__ float Bs_[32][140];
    const int tid = threadIdx.x;

    int chan, row0, M;
    const float *Wroot, *Wrel;
    if ((int)blockIdx.x < Bs) {
        chan = 0; row0 = blockIdx.x * 128; M = Ns;
        Wroot = Ws_root; Wrel = Ws_rel;
    } else {
        chan = 1; row0 = (blockIdx.x - Bs) * 128; M = 3 * Ns;
        Wroot = Wv_root; Wrel = Wv_rel;
    }

    const int trow = (tid >> 4) << 3;
    const int tcol = (tid & 15) << 3;
    const int trs = swz(trow);
    const int tcs = swz(tcol);

    float acc[8][8];
    #pragma unroll
    for (int i = 0; i < 8; i++)
        #pragma unroll
        for (int j = 0; j < 8; j++) acc[i][j] = 0.f;

    for (int phase = 0; phase < 2; phase++) {
        const float* Aglob = (phase == 0) ? x : out;
        const float* W     = (phase == 0) ? Wroot : Wrel;
        for (int kc = 0; kc < 4; kc++) {
            #pragma unroll
            for (int j = 0; j < 4; j++) {
                int flat4 = tid + j * 256;
                int r = flat4 >> 3;
                int kk4 = flat4 & 7;
                int gr = row0 + r;
                float4 v = make_float4(0.f, 0.f, 0.f, 0.f);
                if (gr < M) {
                    size_t base;
                    if (chan == 0) base = (size_t)gr * 512;
                    else { int n = gr / 3; int vv = gr - n * 3;
                           base = (size_t)n * 512 + 128 + (size_t)vv * 128; }
                    v = *(const float4*)(Aglob + base + kc * 32 + kk4 * 4);
                }
                int rs = swz(r);
                As[kk4 * 4 + 0][rs] = v.x;
                As[kk4 * 4 + 1][rs] = v.y;
                As[kk4 * 4 + 2][rs] = v.z;
                As[kk4 * 4 + 3][rs] = v.w;
            }
            #pragma unroll
            for (int j = 0; j < 4; j++) {
                int flat4 = tid + j * 256;
                int o = flat4 >> 3;
                int kk4 = flat4 & 7;
                float4 v = *(const float4*)(W + (size_t)o * 128 + kc * 32 + kk4 * 4);
                int os = swz(o);
                Bs_[kk4 * 4 + 0][os] = v.x;
                Bs_[kk4 * 4 + 1][os] = v.y;
                Bs_[kk4 * 4 + 2][os] = v.z;
                Bs_[kk4 * 4 + 3][os] = v.w;
            }
            __syncthreads();
            #pragma unroll
            for (int kk = 0; kk < 32; kk++) {
                float a[8], b[8];
                #pragma unroll
                for (int i = 0; i < 8; i++) a[i] = As[kk][trs + i];
                #pragma unroll
                for (int j2 = 0; j2 < 8; j2++) b[j2] = Bs_[kk][tcs + j2];
                #pragma unroll
                for (int i = 0; i < 8; i++)
                    #pragma unroll
                    for (int j2 = 0; j2 < 8; j2++)
                        acc[i][j2] = fmaf(a[i], b[j2], acc[i][j2]);
            }
            __syncthreads();
        }
    }

    float bb[8];
    #pragma unroll
    for (int j = 0; j < 8; j++) bb[j] = (chan == 0) ? b_s[tcol + j] : 0.f;

    #pragma unroll
    for (int i = 0; i < 8; i++) {
        int gr = row0 + trow + i;
        if (gr >= M) continue;
        size_t base;
        if (chan == 0) base = (size_t)gr * 512;
        else { int n = gr / 3; int vv = gr - n * 3;
               base = (size_t)n * 512 + 128 + (size_t)vv * 128; }
        float4 v0, v1;
        v0.x = acc[i][0] + bb[0]; v0.y = acc[i][1] + bb[1];
        v0.z = acc[i][2] + bb[2]; v0.w = acc[i][3] + bb[3];
        v1.x = acc[i][4] + bb[4]; v1.y = acc[i][5] + bb[5];
        v1.z = acc[i][6] + bb[6]; v1.w = acc[i][7] + bb[7];
        *(float4*)(out + base + tcol)     = v0;
        *(float4*)(out + base + tcol + 4) = v1;
    }
}

extern "C" void kernel_launch(void* const* d_in, const int* in_sizes, int n_in,
                              void* d_out, int out_size, void* d_ws, size_t ws_size,
                              hipStream_t stream) {
    const float* x        = (const float*)d_in[0];
    const int*   ei       = (const int*)d_in[1];
    const float* W_s_rel  = (const float*)d_in[2];
    const float* W_s_root = (const float*)d_in[3];
    const float* b_s_root = (const float*)d_in[4];
    const float* W_v_rel  = (const float*)d_in[5];
    const float* W_v_root = (const float*)d_in[6];
    float* out = (float*)d_out;

    int N = in_sizes[0] / 512;   // 50000
    int E = in_sizes[1] / 2;     // 500000

    // ws (ints): counts[N] | offsets[N+1] | cursor[N] | bins[E] | blocksums[64]
    int* counts    = (int*)d_ws;
    int* offsets   = counts + N;
    int* cursor    = offsets + N + 1;
    int* bins      = cursor + N;
    int* blocksums = bins + E;

    int nb = (N + 1023) / 1024;  // 49 <= 64

    hipMemsetAsync(counts, 0, (size_t)N * sizeof(int), stream);
    hist_kernel<<<(E + 255) / 256, 256, 0, stream>>>(ei, counts, E);
    scan_local_kernel<<<nb, 1024, 0, stream>>>(counts, offsets, blocksums, N);
    scan_blocksums_kernel<<<1, 64, 0, stream>>>(blocksums, nb);
    scan_add_kernel<<<nb, 1024, 0, stream>>>(offsets, cursor, blocksums, N, E);
    bin_kernel<<<(E + 255) / 256, 256, 0, stream>>>(ei, cursor, bins, E);

    aggregate_kernel<<<N, 128, 0, stream>>>((const float4*)x, offsets, bins,
                                            (float4*)out);

    int Bs = (N + 127) / 128;
    int Bv = (3 * N + 127) / 128;
    transform_kernel<<<Bs + Bv, 256, 0, stream>>>(
        x, out, W_s_root, W_s_rel, b_s_root, W_v_root, W_v_rel, N, Bs);
}

// Round 4
// 402.680 us; speedup vs baseline: 9.0641x; 1.3468x over previous
//
#include <hip/hip_runtime.h>

// EquivariantGraphConvCheap: N=50000, E=500000, H=128.
// R4: transform -> bf16 MFMA (32x32x16), no LDS, fragments gathered directly
//     to registers (fp32 GEMM was LDS-BW bound: 1 B/FMA vs 85 B/cyc/CU).
//     aggregate -> bf16 gather (x converted once; 51 MB L3-resident), fp32 acc.
//     agg stored fp32 in d_out; transform converts in-kernel (in-place safe).

typedef short bfrag __attribute__((ext_vector_type(8)));   // 8 bf16 = 4 VGPR
typedef float cfrag __attribute__((ext_vector_type(16)));  // 32x32 C/D tile

__device__ __forceinline__ short f2bf(float f) {
    unsigned u = __builtin_bit_cast(unsigned, f);
    u += 0x7fff + ((u >> 16) & 1);          // RNE
    return (short)(u >> 16);
}
__device__ __forceinline__ float bf2f(short s) {
    unsigned u = ((unsigned)(unsigned short)s) << 16;
    return __builtin_bit_cast(float, u);
}
__device__ __forceinline__ bfrag pack8(float4 lo, float4 hi) {
    bfrag r;
    r[0] = f2bf(lo.x); r[1] = f2bf(lo.y); r[2] = f2bf(lo.z); r[3] = f2bf(lo.w);
    r[4] = f2bf(hi.x); r[5] = f2bf(hi.y); r[6] = f2bf(hi.z); r[7] = f2bf(hi.w);
    return r;
}

// ---------- CSR build ----------
__global__ __launch_bounds__(256) void hist_kernel(
    const int* __restrict__ ei, int* __restrict__ counts, int E)
{
    int e = blockIdx.x * 256 + threadIdx.x;
    if (e < E) atomicAdd(&counts[ei[e]], 1);
}

__global__ __launch_bounds__(1024) void scan_local_kernel(
    const int* __restrict__ counts, int* __restrict__ offsets,
    int* __restrict__ blocksums, int N)
{
    __shared__ int wsum[16];
    const int tid = threadIdx.x, lane = tid & 63, wid = tid >> 6;
    int i = blockIdx.x * 1024 + tid;
    int v = (i < N) ? counts[i] : 0;
    int incl = v;
    #pragma unroll
    for (int off = 1; off < 64; off <<= 1) {
        int t = __shfl_up(incl, off, 64);
        if (lane >= off) incl += t;
    }
    if (lane == 63) wsum[wid] = incl;
    __syncthreads();
    if (wid == 0) {
        int ws = (lane < 16) ? wsum[lane] : 0;
        int wincl = ws;
        #pragma unroll
        for (int off = 1; off < 16; off <<= 1) {
            int t = __shfl_up(wincl, off, 64);
            if (lane >= off) wincl += t;
        }
        if (lane < 16) wsum[lane] = wincl - ws;
    }
    __syncthreads();
    int excl = incl - v + wsum[wid];
    if (i < N) offsets[i] = excl;
    if (tid == 1023) blocksums[blockIdx.x] = excl + v;
}

__global__ __launch_bounds__(64) void scan_blocksums_kernel(
    int* __restrict__ bs, int nb)
{
    int lane = threadIdx.x;
    int v = (lane < nb) ? bs[lane] : 0;
    int incl = v;
    #pragma unroll
    for (int off = 1; off < 64; off <<= 1) {
        int t = __shfl_up(incl, off, 64);
        if (lane >= off) incl += t;
    }
    if (lane < nb) bs[lane] = incl - v;
}

__global__ __launch_bounds__(1024) void scan_add_kernel(
    int* __restrict__ offsets, int* __restrict__ cursor,
    const int* __restrict__ bs, int N, int E)
{
    int i = blockIdx.x * 1024 + threadIdx.x;
    if (i < N) {
        int v = offsets[i] + bs[blockIdx.x];
        offsets[i] = v;
        cursor[i] = v;
    }
    if (i == 0) offsets[N] = E;
}

__global__ __launch_bounds__(256) void bin_kernel(
    const int* __restrict__ ei, int* __restrict__ cursor,
    int* __restrict__ bins, int E)
{
    int e = blockIdx.x * 256 + threadIdx.x;
    if (e < E) {
        int row = ei[e], col = ei[E + e];
        int pos = atomicAdd(&cursor[row], 1);
        bins[pos] = col;
    }
}

// ---------- conversions ----------
__global__ __launch_bounds__(256) void conv_x_kernel(
    const float* __restrict__ x, short* __restrict__ xbf, long long total8)
{
    long long i = (long long)blockIdx.x * 256 + threadIdx.x;
    if (i >= total8) return;
    float4 lo = *(const float4*)(x + i * 8);
    float4 hi = *(const float4*)(x + i * 8 + 4);
    *(bfrag*)(xbf + i * 8) = pack8(lo, hi);
}

// wbf layout: [Ws_root | Ws_rel | Wv_root | Wv_rel], each 128x128 row-major [o][h]
__global__ __launch_bounds__(256) void conv_w_kernel(
    const float* __restrict__ w0, const float* __restrict__ w1,
    const float* __restrict__ w2, const float* __restrict__ w3,
    short* __restrict__ wbf)
{
    int i = blockIdx.x * 256 + threadIdx.x;   // 0..8191
    int j = i * 8;
    int m = j >> 14, off = j & 16383;
    const float* src = (m == 0) ? w0 : (m == 1) ? w1 : (m == 2) ? w2 : w3;
    float4 lo = *(const float4*)(src + off);
    float4 hi = *(const float4*)(src + off + 4);
    *(bfrag*)(wbf + j) = pack8(lo, hi);
}

// ---------- Phase 1: aggregation (wave = node; writes agg fp32 into out) ----------
template<int XBF>
__global__ __launch_bounds__(256) void aggregate_kernel(
    const float* __restrict__ x, const short* __restrict__ xbf,
    const int* __restrict__ offsets, const int* __restrict__ bins,
    float* __restrict__ out, int Nn)
{
    int n = blockIdx.x * 4 + (threadIdx.x >> 6);
    if (n >= Nn) return;
    int lane = threadIdx.x & 63;             // lane*8 spans (chan, h) of 512-row
    int beg = offsets[n], end = offsets[n + 1];
    float acc[8] = {0, 0, 0, 0, 0, 0, 0, 0};
    int e = beg;
    for (; e + 4 <= end; e += 4) {
        int c0 = bins[e], c1 = bins[e + 1], c2 = bins[e + 2], c3 = bins[e + 3];
        if (XBF) {
            bfrag v0 = *(const bfrag*)(xbf + (size_t)c0 * 512 + lane * 8);
            bfrag v1 = *(const bfrag*)(xbf + (size_t)c1 * 512 + lane * 8);
            bfrag v2 = *(const bfrag*)(xbf + (size_t)c2 * 512 + lane * 8);
            bfrag v3 = *(const bfrag*)(xbf + (size_t)c3 * 512 + lane * 8);
            #pragma unroll
            for (int j = 0; j < 8; j++)
                acc[j] += (bf2f(v0[j]) + bf2f(v1[j])) + (bf2f(v2[j]) + bf2f(v3[j]));
        } else {
            float4 l0 = *(const float4*)(x + (size_t)c0 * 512 + lane * 8);
            float4 h0 = *(const float4*)(x + (size_t)c0 * 512 + lane * 8 + 4);
            float4 l1 = *(const float4*)(x + (size_t)c1 * 512 + lane * 8);
            float4 h1 = *(const float4*)(x + (size_t)c1 * 512 + lane * 8 + 4);
            float4 l2 = *(const float4*)(x + (size_t)c2 * 512 + lane * 8);
            float4 h2 = *(const float4*)(x + (size_t)c2 * 512 + lane * 8 + 4);
            float4 l3 = *(const float4*)(x + (size_t)c3 * 512 + lane * 8);
            float4 h3 = *(const float4*)(x + (size_t)c3 * 512 + lane * 8 + 4);
            acc[0] += (l0.x + l1.x) + (l2.x + l3.x);
            acc[1] += (l0.y + l1.y) + (l2.y + l3.y);
            acc[2] += (l0.z + l1.z) + (l2.z + l3.z);
            acc[3] += (l0.w + l1.w) + (l2.w + l3.w);
            acc[4] += (h0.x + h1.x) + (h2.x + h3.x);
            acc[5] += (h0.y + h1.y) + (h2.y + h3.y);
            acc[6] += (h0.z + h1.z) + (h2.z + h3.z);
            acc[7] += (h0.w + h1.w) + (h2.w + h3.w);
        }
    }
    for (; e < end; e++) {
        int c = bins[e];
        if (XBF) {
            bfrag v = *(const bfrag*)(xbf + (size_t)c * 512 + lane * 8);
            #pragma unroll
            for (int j = 0; j < 8; j++) acc[j] += bf2f(v[j]);
        } else {
            float4 l = *(const float4*)(x + (size_t)c * 512 + lane * 8);
            float4 h = *(const float4*)(x + (size_t)c * 512 + lane * 8 + 4);
            acc[0] += l.x; acc[1] += l.y; acc[2] += l.z; acc[3] += l.w;
            acc[4] += h.x; acc[5] += h.y; acc[6] += h.z; acc[7] += h.w;
        }
    }
    float4 o0 = make_float4(acc[0], acc[1], acc[2], acc[3]);
    float4 o1 = make_float4(acc[4], acc[5], acc[6], acc[7]);
    *(float4*)(out + (size_t)n * 512 + lane * 8)     = o0;
    *(float4*)(out + (size_t)n * 512 + lane * 8 + 4) = o1;
}

// ---------- Phase 2: MFMA transform (no LDS), in-place on out ----------
// block = 32 nodes; wave = channel c (0=scalar uses Ws, 1..3 vector use Wv).
// D[32 rows x 128 cols] = Xrow[32x128]@Wroot^T + Agg[32x128]@Wrel^T (+bias c==0)
// A-frag (32x32x16): A[m=lane&31][k=(lane>>5)*8+j]; B-frag: W[o=lane&31][k=...].
// C/D: col=lane&31, row=(reg&3)+8*(reg>>2)+4*(lane>>5)  [measured m74/m101].
template<int XBF>
__global__ __launch_bounds__(256) void transform_mfma(
    const float* __restrict__ x, const short* __restrict__ xbf,
    float* __restrict__ out, const short* __restrict__ wbf,
    const float* __restrict__ b_s, int Nn)
{
    const int tid = threadIdx.x;
    const int c = tid >> 6;                // wave index = channel
    const int lane = tid & 63;
    const int l31 = lane & 31;
    const int kg = lane >> 5;              // k-group 0/1
    const int n0 = blockIdx.x * 32;
    int m = n0 + l31; if (m >= Nn) m = Nn - 1;          // clamped A-row node
    const size_t arow = ((size_t)m * 4 + c) * 128;      // element offset
    const short* wroot = wbf + ((c == 0) ? 0 : 2) * 16384;
    const short* wrel  = wbf + ((c == 0) ? 1 : 3) * 16384;

    cfrag acc[4];
    #pragma unroll
    for (int t = 0; t < 4; t++)
        #pragma unroll
        for (int r = 0; r < 16; r++) acc[t][r] = 0.f;

    // phase 0: A = root input (x)
    #pragma unroll
    for (int ks = 0; ks < 8; ks++) {
        const int k0 = ks * 16 + kg * 8;
        bfrag a;
        if (XBF) {
            a = *(const bfrag*)(xbf + arow + k0);
        } else {
            float4 lo = *(const float4*)(x + arow + k0);
            float4 hi = *(const float4*)(x + arow + k0 + 4);
            a = pack8(lo, hi);
        }
        #pragma unroll
        for (int t = 0; t < 4; t++) {
            bfrag b = *(const bfrag*)(wroot + (size_t)(t * 32 + l31) * 128 + k0);
            acc[t] = __builtin_amdgcn_mfma_f32_32x32x16_bf16(a, b, acc[t], 0, 0, 0);
        }
    }
    // phase 1: A = aggregated neighbors (fp32, lives in out)
    #pragma unroll
    for (int ks = 0; ks < 8; ks++) {
        const int k0 = ks * 16 + kg * 8;
        float4 lo = *(const float4*)(out + arow + k0);
        float4 hi = *(const float4*)(out + arow + k0 + 4);
        bfrag a = pack8(lo, hi);
        #pragma unroll
        for (int t = 0; t < 4; t++) {
            bfrag b = *(const bfrag*)(wrel + (size_t)(t * 32 + l31) * 128 + k0);
            acc[t] = __builtin_amdgcn_mfma_f32_32x32x16_bf16(a, b, acc[t], 0, 0, 0);
        }
    }

    float bv[4] = {0.f, 0.f, 0.f, 0.f};
    if (c == 0) {
        #pragma unroll
        for (int t = 0; t < 4; t++) bv[t] = b_s[t * 32 + l31];
    }

    #pragma unroll
    for (int t = 0; t < 4; t++) {
        #pragma unroll
        for (int r = 0; r < 16; r++) {
            int row = (r & 3) + 8 * (r >> 2) + 4 * kg;
            int node = n0 + row;
            if (node < Nn)
                out[((size_t)node * 4 + c) * 128 + t * 32 + l31] = acc[t][r] + bv[t];
        }
    }
}

extern "C" void kernel_launch(void* const* d_in, const int* in_sizes, int n_in,
                              void* d_out, int out_size, void* d_ws, size_t ws_size,
                              hipStream_t stream) {
    const float* x        = (const float*)d_in[0];
    const int*   ei       = (const int*)d_in[1];
    const float* W_s_rel  = (const float*)d_in[2];
    const float* W_s_root = (const float*)d_in[3];
    const float* b_s_root = (const float*)d_in[4];
    const float* W_v_rel  = (const float*)d_in[5];
    const float* W_v_root = (const float*)d_in[6];
    float* out = (float*)d_out;

    int N = in_sizes[0] / 512;   // 50000
    int E = in_sizes[1] / 2;     // 500000

    // ws layout: wbf[65536 shorts] | (xbf[N*512 shorts] if it fits) | ints:
    //   counts[N] offsets[N+1] cursor[N] bins[E] blocksums[64]
    size_t ints_bytes = ((size_t)(3 * N + 1) + E + 64) * sizeof(int);
    size_t wbf_bytes  = 65536 * sizeof(short);
    size_t xbf_bytes  = (size_t)N * 512 * sizeof(short);
    bool use_bf = (ws_size >= wbf_bytes + xbf_bytes + ints_bytes);

    short* wbf = (short*)d_ws;
    short* xbf = wbf + 65536;
    int* counts = use_bf ? (int*)(xbf + (size_t)N * 512) : (int*)xbf;
    int* offsets   = counts + N;
    int* cursor    = offsets + N + 1;
    int* bins      = cursor + N;
    int* blocksums = bins + E;

    int nb = (N + 1023) / 1024;

    hipMemsetAsync(counts, 0, (size_t)N * sizeof(int), stream);
    hist_kernel<<<(E + 255) / 256, 256, 0, stream>>>(ei, counts, E);
    scan_local_kernel<<<nb, 1024, 0, stream>>>(counts, offsets, blocksums, N);
    scan_blocksums_kernel<<<1, 64, 0, stream>>>(blocksums, nb);
    scan_add_kernel<<<nb, 1024, 0, stream>>>(offsets, cursor, blocksums, N, E);
    bin_kernel<<<(E + 255) / 256, 256, 0, stream>>>(ei, cursor, bins, E);

    conv_w_kernel<<<32, 256, 0, stream>>>(W_s_root, W_s_rel, W_v_root, W_v_rel, wbf);

    if (use_bf) {
        long long total8 = (long long)N * 64;   // N*512/8
        conv_x_kernel<<<(int)((total8 + 255) / 256), 256, 0, stream>>>(x, xbf, total8);
        aggregate_kernel<1><<<(N + 3) / 4, 256, 0, stream>>>(x, xbf, offsets, bins, out, N);
        transform_mfma<1><<<(N + 31) / 32, 256, 0, stream>>>(x, xbf, out, wbf, b_s_root, N);
    } else {
        aggregate_kernel<0><<<(N + 3) / 4, 256, 0, stream>>>(x, nullptr, offsets, bins, out, N);
        transform_mfma<0><<<(N + 31) / 32, 256, 0, stream>>>(x, nullptr, out, wbf, b_s_root, N);
    }
}